// Round 2
// baseline (387.304 us; speedup 1.0000x reference)
//
#include <hip/hip_runtime.h>
#include <cfloat>

// Problem constants (match setup_inputs)
#define BB 4
#define NN 2000
#define MM 2000
#define KK 16
#define D_IN 34      // 2K+2
#define E1 128
#define E2 256
#define PEN -10.0f
#define EPSV 1e-5f
#define ROWS (BB*NN) // 8000

// ws float-offsets
#define OFF_H2  ((size_t)0)                         // ROWS*E2      = 2,048,000
#define OFF_SD  (OFF_H2 + (size_t)ROWS*E2)          // ROWS*KK      = 128,000
#define OFF_SI  (OFF_SD + (size_t)ROWS*KK)          // ROWS*KK ints
#define OFF_ST  (OFF_SI + (size_t)ROWS*KK)          // 2*BB*E2      = 2,048
#define OFF_W1T (OFF_ST + (size_t)2*BB*E2)          // D_IN*E1
#define OFF_W2T (OFF_W1T + (size_t)D_IN*E1)         // E1*E2
#define OFF_W3T (OFF_W2T + (size_t)E1*E2)           // E2*E1
#define OFF_W4T (OFF_W3T + (size_t)E2*E1)           // E1*KK
#define WS_FLOATS (OFF_W4T + (size_t)E1*KK)         // ~2.38M floats ≈ 9.5 MB

// ---------------- weight transpose (coalesced reads in MLP kernels) --------
__global__ void k_prep(const float* __restrict__ W1, const float* __restrict__ W2,
                       const float* __restrict__ W3, const float* __restrict__ W4,
                       float* __restrict__ ws) {
    int i = blockIdx.x * 256 + threadIdx.x;
    if (i < D_IN*E1) { int k = i / E1, t = i % E1; ws[OFF_W1T + i] = W1[t*D_IN + k]; return; }
    i -= D_IN*E1;
    if (i < E1*E2) { int k = i / E2, c = i % E2; ws[OFF_W2T + (size_t)k*E2 + c] = W2[c*E1 + k]; return; }
    i -= E1*E2;
    if (i < E2*E1) { int k = i / E1, c = i % E1; ws[OFF_W3T + (size_t)k*E1 + c] = W3[c*E2 + k]; return; }
    i -= E2*E1;
    if (i < E1*KK) { int k = i / KK, c = i % KK; ws[OFF_W4T + (size_t)k*KK + c] = W4[c*E1 + k]; }
}

// ---------------- kernel 1: topk(16 smallest, idx-tiebreak) + layers 1,2 ---
__global__ __launch_bounds__(256) void k1_topk_mlp(
    const float* __restrict__ theta, const float* __restrict__ dist,
    const float* __restrict__ ins,  // [2,B,N]
    const float* __restrict__ b1, const float* __restrict__ b2,
    float* __restrict__ ws)
{
    const int row = blockIdx.x;            // b*N+n
    const int b = row / NN, n = row % NN;
    const int t = threadIdx.x;

    __shared__ float vals[MM];
    __shared__ float redv[4]; __shared__ int redi[4];
    __shared__ float sdv[KK]; __shared__ int sid[KK];
    __shared__ float xbuf[D_IN];
    __shared__ float h1[E1];

    // stage dist row in LDS (float4)
    const float4* d4 = (const float4*)(dist + (size_t)row * MM);
    float4* v4 = (float4*)vals;
    for (int i = t; i < MM/4; i += 256) v4[i] = d4[i];
    __syncthreads();

    // 16 × block argmin with (value, index) lexicographic order
    for (int it = 0; it < KK; ++it) {
        float mv = FLT_MAX; int mi = -1;
        for (int i = t; i < MM; i += 256) {
            float v = vals[i];
            if (v < mv || (v == mv && i < mi)) { mv = v; mi = i; }
        }
        #pragma unroll
        for (int off = 32; off; off >>= 1) {
            float ov = __shfl_down(mv, off);
            int   oi = __shfl_down(mi, off);
            if (ov < mv || (ov == mv && oi < mi)) { mv = ov; mi = oi; }
        }
        int wid = t >> 6;
        if ((t & 63) == 0) { redv[wid] = mv; redi[wid] = mi; }
        __syncthreads();
        if (t == 0) {
            mv = redv[0]; mi = redi[0];
            #pragma unroll
            for (int w = 1; w < 4; ++w) {
                float ov = redv[w]; int oi = redi[w];
                if (ov < mv || (ov == mv && oi < mi)) { mv = ov; mi = oi; }
            }
            sdv[it] = mv; sid[it] = mi;
            vals[mi] = FLT_MAX;   // mask out for next iteration
        }
        __syncthreads();
    }

    // normalize sorted_dist by its max (= last element), gather theta, build x
    const float dmax = sdv[KK-1];
    if (t < KK) {
        float nd = sdv[t] / dmax;
        int   id = sid[t];
        xbuf[t]        = nd;
        xbuf[KK + t]   = theta[(size_t)row * MM + id];
        ws[OFF_SD + (size_t)row*KK + t] = nd;
        ((int*)(ws + OFF_SI))[(size_t)row*KK + t] = id;
    }
    if (t == 0) {
        xbuf[2*KK]     = ins[(size_t)b*NN + n];
        xbuf[2*KK + 1] = ins[(size_t)BB*NN + (size_t)b*NN + n];
    }
    __syncthreads();

    // layer 1: 34 -> 128, relu  (W1T[k][t] coalesced)
    if (t < E1) {
        float acc = b1[t];
        #pragma unroll
        for (int k = 0; k < D_IN; ++k) acc += xbuf[k] * ws[OFF_W1T + (size_t)k*E1 + t];
        h1[t] = fmaxf(acc, 0.0f);
    }
    __syncthreads();

    // layer 2: 128 -> 256, relu  (W2T[k][t] coalesced, h1 broadcast from LDS)
    {
        float acc = b2[t];
        #pragma unroll 8
        for (int k = 0; k < E1; ++k) acc += h1[k] * ws[OFF_W2T + (size_t)k*E2 + t];
        ws[OFF_H2 + (size_t)row*E2 + t] = fmaxf(acc, 0.0f);
    }
}

// ---------------- kernel 2: InstanceNorm statistics over N ----------------
#define CHUNK 50
#define NCHUNK (NN/CHUNK)   // 40
__global__ __launch_bounds__(256) void k2_stats(float* __restrict__ ws)
{
    const int b = blockIdx.x / NCHUNK;
    const int ch = blockIdx.x % NCHUNK;
    const int c = threadIdx.x;
    const float* p = ws + OFF_H2 + ((size_t)b*NN + (size_t)ch*CHUNK) * E2 + c;
    float s1 = 0.f, s2 = 0.f;
    #pragma unroll 5
    for (int r = 0; r < CHUNK; ++r) { float v = p[(size_t)r*E2]; s1 += v; s2 += v*v; }
    atomicAdd(&ws[OFF_ST + (size_t)b*E2 + c], s1);
    atomicAdd(&ws[OFF_ST + (size_t)BB*E2 + (size_t)b*E2 + c], s2);
}

// ---------------- kernel 3: norm + layers 3,4 + fill + scatter ------------
__global__ __launch_bounds__(256) void k3_norm_out(
    const float* __restrict__ b3, const float* __restrict__ b4,
    const float* __restrict__ gamma, const float* __restrict__ beta,
    const float* __restrict__ ws, float* __restrict__ out)
{
    const int row = blockIdx.x;
    const int b = row / NN;
    const int t = threadIdx.x;

    __shared__ float hn[E2];
    __shared__ float h3[E1];
    __shared__ float o16[KK];

    // normalize h2 (biased variance, eps inside sqrt)
    {
        float s1 = ws[OFF_ST + (size_t)b*E2 + t];
        float s2 = ws[OFF_ST + (size_t)BB*E2 + (size_t)b*E2 + t];
        float mu  = s1 / (float)NN;
        float var = s2 / (float)NN - mu*mu;
        float inv = 1.0f / sqrtf(var + EPSV);
        float v = ws[OFF_H2 + (size_t)row*E2 + t];
        hn[t] = (v - mu) * inv * gamma[t] + beta[t];
    }
    __syncthreads();

    // layer 3: 256 -> 128, relu
    if (t < E1) {
        float acc = b3[t];
        #pragma unroll 8
        for (int k = 0; k < E2; ++k) acc += hn[k] * ws[OFF_W3T + (size_t)k*E1 + t];
        h3[t] = fmaxf(acc, 0.0f);
    }
    __syncthreads();

    // layer 4: 128 -> 16, minus normalized sorted_dist
    if (t < KK) {
        float acc = b4[t];
        #pragma unroll 8
        for (int k = 0; k < E1; ++k) acc += h3[k] * ws[OFF_W4T + (size_t)k*KK + t];
        o16[t] = acc - ws[OFF_SD + (size_t)row*KK + t];
    }
    __syncthreads();

    // fill row with PENALTY (float4), then scatter the 16 outputs
    float* orow = out + (size_t)row * MM;
    float4* o4 = (float4*)orow;
    const float4 pv = make_float4(PEN, PEN, PEN, PEN);
    for (int i = t; i < MM/4; i += 256) o4[i] = pv;
    __syncthreads();
    if (t < KK) {
        int id = ((const int*)(ws + OFF_SI))[(size_t)row*KK + t];
        orow[id] = o16[t];
    }
}

extern "C" void kernel_launch(void* const* d_in, const int* in_sizes, int n_in,
                              void* d_out, int out_size, void* d_ws, size_t ws_size,
                              hipStream_t stream) {
    const float* theta = (const float*)d_in[0];
    const float* dist  = (const float*)d_in[1];
    const float* ins   = (const float*)d_in[2];
    const float* W1 = (const float*)d_in[3];
    const float* b1 = (const float*)d_in[4];
    const float* W2 = (const float*)d_in[5];
    const float* b2 = (const float*)d_in[6];
    const float* W3 = (const float*)d_in[7];
    const float* b3 = (const float*)d_in[8];
    const float* W4 = (const float*)d_in[9];
    const float* b4 = (const float*)d_in[10];
    const float* gamma = (const float*)d_in[11];
    const float* beta  = (const float*)d_in[12];
    float* ws  = (float*)d_ws;
    float* out = (float*)d_out;

    // zero the stats accumulators (ws is poisoned 0xAA before every launch)
    hipMemsetAsync(ws + OFF_ST, 0, (size_t)2*BB*E2*sizeof(float), stream);

    // weight transposes
    {
        int total = D_IN*E1 + E1*E2 + E2*E1 + E1*KK;
        k_prep<<<(total + 255)/256, 256, 0, stream>>>(W1, W2, W3, W4, ws);
    }
    k1_topk_mlp<<<ROWS, 256, 0, stream>>>(theta, dist, ins, b1, b2, ws);
    k2_stats<<<BB*NCHUNK, 256, 0, stream>>>(ws);
    k3_norm_out<<<ROWS, 256, 0, stream>>>(b3, b4, gamma, beta, ws, out);
}